// Round 1
// baseline (239.411 us; speedup 1.0000x reference)
//
#include <hip/hip_runtime.h>
#include <stdint.h>

typedef unsigned short u16;
typedef __attribute__((ext_vector_type(8))) short short8;
typedef __attribute__((ext_vector_type(4))) float f32x4;

// Problem constants (fixed by setup_inputs)
#define BB 4
#define NN 8192
#define SS 2048
#define MTOT 32768          // B*N
#define CSKIP 256
#define CLO 512
#define CIN 768
#define COUT 256

__device__ __forceinline__ u16 f2bf(float f) {
  unsigned u = __float_as_uint(f);
  u += 0x7fffu + ((u >> 16) & 1u);
  return (u16)(u >> 16);
}

// ---------------------------------------------------------------------------
// K0: convert + transpose weights to bf16: W1T[n][k] (256x768), W2T[n][k] (256x256)
// ---------------------------------------------------------------------------
__global__ __launch_bounds__(256) void wconv_kernel(const float* __restrict__ W1,
                                                    const float* __restrict__ W2,
                                                    u16* __restrict__ W1T,
                                                    u16* __restrict__ W2T) {
  int i = blockIdx.x * 256 + threadIdx.x;
  if (i < CIN * COUT) {                 // 196608
    int n = i / CIN, k = i - n * CIN;
    W1T[i] = f2bf(W1[(size_t)k * COUT + n]);
  } else if (i < CIN * COUT + COUT * COUT) {
    int j = i - CIN * COUT;
    int n = j >> 8, k = j & 255;
    W2T[j] = f2bf(W2[(size_t)k * COUT + n]);
  }
}

// ---------------------------------------------------------------------------
// K1: KNN (K=3, fp64 distances) + IDW interpolation + build fused bf16 [M][768]
// block = 256 threads, 64 queries/block (4 threads per query), grid = M/64
// ---------------------------------------------------------------------------
__global__ __launch_bounds__(256) void knn_interp_kernel(
    const float* __restrict__ xyz_hi, const float* __restrict__ xyz_lo,
    const float* __restrict__ feat_skip, const float* __restrict__ feat_lo,
    u16* __restrict__ fused) {
  __shared__ float lx[SS], ly[SS], lz[SS];
  __shared__ double md[64][12];
  __shared__ int   mi[64][12];
  __shared__ float wq[64][3];
  __shared__ int   iq[64][3];

  int tid = threadIdx.x;
  int blk = blockIdx.x;
  int b = blk >> 7;                       // 128 blocks per batch
  const float* xl = xyz_lo + (size_t)b * SS * 3;
  for (int j = tid; j < SS; j += 256) {
    lx[j] = xl[j * 3 + 0];
    ly[j] = xl[j * 3 + 1];
    lz[j] = xl[j * 3 + 2];
  }
  __syncthreads();

  int q = tid >> 2, part = tid & 3;
  int qm = blk * 64 + q;
  double qx = (double)xyz_hi[(size_t)qm * 3 + 0];
  double qy = (double)xyz_hi[(size_t)qm * 3 + 1];
  double qz = (double)xyz_hi[(size_t)qm * 3 + 2];

  double bd0 = 1e300, bd1 = 1e300, bd2 = 1e300;
  int bi0 = -1, bi1 = -1, bi2 = -1;
  int j0 = part * 512;
  for (int j = j0; j < j0 + 512; ++j) {
    double dx = (double)lx[j] - qx;
    double dy = (double)ly[j] - qy;
    double dz = (double)lz[j] - qz;
    double d2 = dx * dx + dy * dy + dz * dz;
    if (d2 < bd2) {
      bd2 = d2; bi2 = j;
      if (bd2 < bd1) { double t = bd1; bd1 = bd2; bd2 = t; int ti = bi1; bi1 = bi2; bi2 = ti; }
      if (bd1 < bd0) { double t = bd0; bd0 = bd1; bd1 = t; int ti = bi0; bi0 = bi1; bi1 = ti; }
    }
  }
  md[q][part * 3 + 0] = bd0; mi[q][part * 3 + 0] = bi0;
  md[q][part * 3 + 1] = bd1; mi[q][part * 3 + 1] = bi1;
  md[q][part * 3 + 2] = bd2; mi[q][part * 3 + 2] = bi2;
  __syncthreads();

  if (part == 0) {
    double fb0 = 1e300, fb1 = 1e300, fb2 = 1e300;
    int fi0 = -1, fi1 = -1, fi2 = -1;
    // parts cover ascending index ranges, each sorted ascending: strict-< insert
    // reproduces stable (index-tiebreak) top-k.
    for (int u = 0; u < 12; ++u) {
      double d2 = md[q][u]; int idx = mi[q][u];
      if (d2 < fb2) {
        fb2 = d2; fi2 = idx;
        if (fb2 < fb1) { double t = fb1; fb1 = fb2; fb2 = t; int ti = fi1; fi1 = fi2; fi2 = ti; }
        if (fb1 < fb0) { double t = fb0; fb0 = fb1; fb1 = t; int ti = fi0; fi0 = fi1; fi1 = ti; }
      }
    }
    float d0 = (float)sqrt(fb0);
    float d1 = (float)sqrt(fb1);
    float d2f = (float)sqrt(fb2);
    float inv0 = 1.0f / (d0 + 1e-8f);
    float inv1 = 1.0f / (d1 + 1e-8f);
    float inv2 = 1.0f / (d2f + 1e-8f);
    float s = inv0 + inv1 + inv2;
    wq[q][0] = inv0 / s; wq[q][1] = inv1 / s; wq[q][2] = inv2 / s;
    iq[q][0] = fi0; iq[q][1] = fi1; iq[q][2] = fi2;
  }
  __syncthreads();

  // interpolation + skip copy: wave-per-query, lane covers 8 interp ch / 4 skip ch
  int wid = tid >> 6, lane = tid & 63;
  for (int qq = wid; qq < 64; qq += 4) {
    int qm2 = blk * 64 + qq;
    float w0 = wq[qq][0], w1 = wq[qq][1], w2 = wq[qq][2];
    const float* f0 = feat_lo + ((size_t)b * SS + iq[qq][0]) * CLO + lane * 8;
    const float* f1 = feat_lo + ((size_t)b * SS + iq[qq][1]) * CLO + lane * 8;
    const float* f2 = feat_lo + ((size_t)b * SS + iq[qq][2]) * CLO + lane * 8;
    float4 a0 = ((const float4*)f0)[0], a1 = ((const float4*)f0)[1];
    float4 c0 = ((const float4*)f1)[0], c1 = ((const float4*)f1)[1];
    float4 e0 = ((const float4*)f2)[0], e1 = ((const float4*)f2)[1];
    float av[8];
    av[0] = w0 * a0.x + w1 * c0.x + w2 * e0.x;
    av[1] = w0 * a0.y + w1 * c0.y + w2 * e0.y;
    av[2] = w0 * a0.z + w1 * c0.z + w2 * e0.z;
    av[3] = w0 * a0.w + w1 * c0.w + w2 * e0.w;
    av[4] = w0 * a1.x + w1 * c1.x + w2 * e1.x;
    av[5] = w0 * a1.y + w1 * c1.y + w2 * e1.y;
    av[6] = w0 * a1.z + w1 * c1.z + w2 * e1.z;
    av[7] = w0 * a1.w + w1 * c1.w + w2 * e1.w;
    u16 ph[8];
#pragma unroll
    for (int c = 0; c < 8; ++c) ph[c] = f2bf(av[c]);
    uint4 st; __builtin_memcpy(&st, ph, 16);
    *(uint4*)(fused + (size_t)qm2 * CIN + CSKIP + lane * 8) = st;

    float4 sk = *(const float4*)(feat_skip + (size_t)qm2 * CSKIP + lane * 4);
    u16 p4[4];
    p4[0] = f2bf(sk.x); p4[1] = f2bf(sk.y); p4[2] = f2bf(sk.z); p4[3] = f2bf(sk.w);
    uint2 st2; __builtin_memcpy(&st2, p4, 8);
    *(uint2*)(fused + (size_t)qm2 * CIN + lane * 4) = st2;
  }
}

// ---------------------------------------------------------------------------
// K2: GEMM1  h = relu(fused @ W1 + b1), bf16 MFMA 16x16x32
// tile 128x128, 256 threads (4 waves, 2x2), BK=32, K=768
// ---------------------------------------------------------------------------
__global__ __launch_bounds__(256) void gemm1_kernel(const u16* __restrict__ A,
                                                    const u16* __restrict__ Bt,
                                                    const float* __restrict__ b1,
                                                    u16* __restrict__ H) {
  __shared__ u16 As[128 * 32];
  __shared__ u16 Bs[128 * 32];
  int tid = threadIdx.x;
  int bm = blockIdx.x >> 1, bn = blockIdx.x & 1;
  int m0 = bm << 7, n0 = bn << 7;
  int w = tid >> 6, lane = tid & 63;
  int wr = w >> 1, wc = w & 1;
  int quad = lane >> 4, l16 = lane & 15;

  f32x4 zero = {0.f, 0.f, 0.f, 0.f};
  f32x4 acc[4][4];
#pragma unroll
  for (int tm = 0; tm < 4; ++tm)
#pragma unroll
    for (int tn = 0; tn < 4; ++tn) acc[tm][tn] = zero;

  for (int k0 = 0; k0 < CIN; k0 += 32) {
    __syncthreads();
#pragma unroll
    for (int r = 0; r < 2; ++r) {
      int u = tid + r * 256;
      int row = u >> 2, kk = (u & 3) << 3;
      ((uint4*)As)[u] = *(const uint4*)(A + (size_t)(m0 + row) * CIN + k0 + kk);
      ((uint4*)Bs)[u] = *(const uint4*)(Bt + (size_t)(n0 + row) * CIN + k0 + kk);
    }
    __syncthreads();
    short8 af[4], bf[4];
#pragma unroll
    for (int t = 0; t < 4; ++t)
      af[t] = *(const short8*)(As + ((wr * 64 + t * 16 + l16) * 32 + quad * 8));
#pragma unroll
    for (int t = 0; t < 4; ++t)
      bf[t] = *(const short8*)(Bs + ((wc * 64 + t * 16 + l16) * 32 + quad * 8));
#pragma unroll
    for (int tm = 0; tm < 4; ++tm)
#pragma unroll
      for (int tn = 0; tn < 4; ++tn)
        acc[tm][tn] = __builtin_amdgcn_mfma_f32_16x16x32_bf16(af[tm], bf[tn], acc[tm][tn], 0, 0, 0);
  }

  float bias[4];
#pragma unroll
  for (int tn = 0; tn < 4; ++tn) bias[tn] = b1[n0 + wc * 64 + tn * 16 + l16];
#pragma unroll
  for (int tm = 0; tm < 4; ++tm)
#pragma unroll
    for (int tn = 0; tn < 4; ++tn) {
      int col = n0 + wc * 64 + tn * 16 + l16;
#pragma unroll
      for (int r = 0; r < 4; ++r) {
        int row = m0 + wr * 64 + tm * 16 + quad * 4 + r;
        float v = acc[tm][tn][r] + bias[tn];
        v = v > 0.f ? v : 0.f;
        H[(size_t)row * COUT + col] = f2bf(v);
      }
    }
}

// ---------------------------------------------------------------------------
// K3: GEMM2 + bias + LayerNorm. tile 128x256 (full width), 512 threads (2x4
// waves), K=256. LN stats via shfl_xor + LDS cross-wave reduction.
// ---------------------------------------------------------------------------
__global__ __launch_bounds__(512) void gemm2_ln_kernel(const u16* __restrict__ H,
                                                       const u16* __restrict__ Bt,
                                                       const float* __restrict__ b2,
                                                       const float* __restrict__ gamma,
                                                       const float* __restrict__ beta,
                                                       float* __restrict__ out) {
  __shared__ u16 As[128 * 32];
  __shared__ u16 Bs[256 * 32];
  __shared__ float red[4][128][2];
  __shared__ float stats[128][2];
  int tid = threadIdx.x;
  int m0 = blockIdx.x << 7;
  int w = tid >> 6, lane = tid & 63;
  int wr = w >> 2, wc = w & 3;
  int quad = lane >> 4, l16 = lane & 15;

  f32x4 zero = {0.f, 0.f, 0.f, 0.f};
  f32x4 acc[4][4];
#pragma unroll
  for (int tm = 0; tm < 4; ++tm)
#pragma unroll
    for (int tn = 0; tn < 4; ++tn) acc[tm][tn] = zero;

  for (int k0 = 0; k0 < COUT; k0 += 32) {
    __syncthreads();
    {
      int row = tid >> 2, kk = (tid & 3) << 3;
      ((uint4*)As)[tid] = *(const uint4*)(H + (size_t)(m0 + row) * COUT + k0 + kk);
#pragma unroll
      for (int r = 0; r < 2; ++r) {
        int ub = tid + r * 512;
        int nrow = ub >> 2, kb = (ub & 3) << 3;
        ((uint4*)Bs)[ub] = *(const uint4*)(Bt + (size_t)nrow * COUT + k0 + kb);
      }
    }
    __syncthreads();
    short8 af[4], bf[4];
#pragma unroll
    for (int t = 0; t < 4; ++t)
      af[t] = *(const short8*)(As + ((wr * 64 + t * 16 + l16) * 32 + quad * 8));
#pragma unroll
    for (int t = 0; t < 4; ++t)
      bf[t] = *(const short8*)(Bs + ((wc * 64 + t * 16 + l16) * 32 + quad * 8));
#pragma unroll
    for (int tm = 0; tm < 4; ++tm)
#pragma unroll
      for (int tn = 0; tn < 4; ++tn)
        acc[tm][tn] = __builtin_amdgcn_mfma_f32_16x16x32_bf16(af[tm], bf[tn], acc[tm][tn], 0, 0, 0);
  }

  float bias[4], g[4], be[4];
#pragma unroll
  for (int tn = 0; tn < 4; ++tn) {
    int col = wc * 64 + tn * 16 + l16;
    bias[tn] = b2[col]; g[tn] = gamma[col]; be[tn] = beta[col];
  }
#pragma unroll
  for (int tm = 0; tm < 4; ++tm)
#pragma unroll
    for (int r = 0; r < 4; ++r) {
      float s = 0.f, sq = 0.f;
#pragma unroll
      for (int tn = 0; tn < 4; ++tn) {
        float v = acc[tm][tn][r] + bias[tn];
        acc[tm][tn][r] = v;
        s += v; sq += v * v;
      }
#pragma unroll
      for (int msk = 1; msk < 16; msk <<= 1) {
        s += __shfl_xor(s, msk);
        sq += __shfl_xor(sq, msk);
      }
      if (l16 == 0) {
        int rl = wr * 64 + tm * 16 + quad * 4 + r;
        red[wc][rl][0] = s;
        red[wc][rl][1] = sq;
      }
    }
  __syncthreads();
  if (tid < 128) {
    float s = red[0][tid][0] + red[1][tid][0] + red[2][tid][0] + red[3][tid][0];
    float sq = red[0][tid][1] + red[1][tid][1] + red[2][tid][1] + red[3][tid][1];
    float mu = s * (1.f / 256.f);
    float var = sq * (1.f / 256.f) - mu * mu;
    stats[tid][0] = mu;
    stats[tid][1] = rsqrtf(var + 1e-5f);
  }
  __syncthreads();
#pragma unroll
  for (int tm = 0; tm < 4; ++tm)
#pragma unroll
    for (int r = 0; r < 4; ++r) {
      int rl = wr * 64 + tm * 16 + quad * 4 + r;
      float mu = stats[rl][0], rstd = stats[rl][1];
#pragma unroll
      for (int tn = 0; tn < 4; ++tn) {
        int col = wc * 64 + tn * 16 + l16;
        out[(size_t)(m0 + rl) * COUT + col] = (acc[tm][tn][r] - mu) * rstd * g[tn] + be[tn];
      }
    }
}

// ---------------------------------------------------------------------------
extern "C" void kernel_launch(void* const* d_in, const int* in_sizes, int n_in,
                              void* d_out, int out_size, void* d_ws, size_t ws_size,
                              hipStream_t stream) {
  const float* xyz_hi    = (const float*)d_in[0];
  const float* xyz_lo    = (const float*)d_in[1];
  const float* feat_skip = (const float*)d_in[2];
  const float* feat_lo   = (const float*)d_in[3];
  const float* W1        = (const float*)d_in[4];
  const float* b1        = (const float*)d_in[5];
  const float* W2        = (const float*)d_in[6];
  const float* b2        = (const float*)d_in[7];
  const float* gamma     = (const float*)d_in[8];
  const float* beta      = (const float*)d_in[9];
  float* out = (float*)d_out;

  char* ws = (char*)d_ws;
  u16* fused = (u16*)ws;                                   // 32768*768*2 = 50331648
  u16* H     = (u16*)(ws + 50331648);                      // 32768*256*2 = 16777216
  u16* W1T   = (u16*)(ws + 50331648 + 16777216);           // 256*768*2   = 393216
  u16* W2T   = (u16*)(ws + 50331648 + 16777216 + 393216);  // 256*256*2

  wconv_kernel<<<1024, 256, 0, stream>>>(W1, W2, W1T, W2T);
  knn_interp_kernel<<<MTOT / 64, 256, 0, stream>>>(xyz_hi, xyz_lo, feat_skip, feat_lo, fused);
  gemm1_kernel<<<(MTOT / 128) * 2, 256, 0, stream>>>(fused, W1T, b1, H);
  gemm2_ln_kernel<<<MTOT / 128, 512, 0, stream>>>(H, W2T, b2, gamma, beta, out);
}

// Round 2
// 208.638 us; speedup vs baseline: 1.1475x; 1.1475x over previous
//
#include <hip/hip_runtime.h>
#include <stdint.h>

typedef unsigned short u16;
typedef __attribute__((ext_vector_type(8))) short short8;
typedef __attribute__((ext_vector_type(4))) float f32x4;

#define BB 4
#define NN 8192
#define SS 2048
#define MTOT 32768
#define CSKIP 256
#define CLO 512
#define CIN 768
#define COUT 256
#define QPB 32              // queries per knn block
#define PARTS 8             // threads per query

__device__ __forceinline__ u16 f2bf(float f) {
  unsigned u = __float_as_uint(f);
  u += 0x7fffu + ((u >> 16) & 1u);
  return (u16)(u >> 16);
}

__device__ __forceinline__ void gl_lds16(const void* g, void* l) {
  __builtin_amdgcn_global_load_lds(
      (const __attribute__((address_space(1))) void*)g,
      (__attribute__((address_space(3))) void*)l, 16, 0, 0);
}

// ---------------------------------------------------------------------------
// K0: weights -> bf16 transposed [n][k]
// ---------------------------------------------------------------------------
__global__ __launch_bounds__(256) void wconv_kernel(const float* __restrict__ W1,
                                                    const float* __restrict__ W2,
                                                    u16* __restrict__ W1T,
                                                    u16* __restrict__ W2T) {
  int i = blockIdx.x * 256 + threadIdx.x;
  if (i < CIN * COUT) {
    int n = i / CIN, k = i - n * CIN;
    W1T[i] = f2bf(W1[(size_t)k * COUT + n]);
  } else if (i < CIN * COUT + COUT * COUT) {
    int j = i - CIN * COUT;
    int n = j >> 8, k = j & 255;
    W2T[j] = f2bf(W2[(size_t)k * COUT + n]);
  }
}

// ---------------------------------------------------------------------------
// K1: KNN (K=3, fp32 diff-form distances) + IDW interp + fused bf16 [M][768]
// 256 thr, 32 queries/block (8 threads/query, strided partitions), grid=1024
// ---------------------------------------------------------------------------
__global__ __launch_bounds__(256, 4) void knn_interp_kernel(
    const float* __restrict__ xyz_hi, const float* __restrict__ xyz_lo,
    const float* __restrict__ feat_skip, const float* __restrict__ feat_lo,
    u16* __restrict__ fused) {
  __shared__ float4 sxyz[SS];        // 32 KB
  __shared__ float md[QPB][25];      // padded to 25 (bank stride)
  __shared__ int   mi[QPB][25];
  __shared__ float wq[QPB][3];
  __shared__ int   iq[QPB][3];

  int tid = threadIdx.x;
  int blk = blockIdx.x;
  int b = blk >> 8;                  // 256 blocks per batch
  const float* xl = xyz_lo + (size_t)b * SS * 3;
  for (int j = tid; j < SS; j += 256)
    sxyz[j] = make_float4(xl[j * 3 + 0], xl[j * 3 + 1], xl[j * 3 + 2], 0.f);
  __syncthreads();

  int q = tid >> 3, part = tid & 7;
  int qm = blk * QPB + q;
  float qx = xyz_hi[(size_t)qm * 3 + 0];
  float qy = xyz_hi[(size_t)qm * 3 + 1];
  float qz = xyz_hi[(size_t)qm * 3 + 2];

  float bd0 = 1e30f, bd1 = 1e30f, bd2 = 1e30f;
  int bi0 = -1, bi1 = -1, bi2 = -1;
  // strided partition: part p scans j = p, p+8, ... (ascending -> stable)
#pragma unroll 4
  for (int i = 0; i < SS / PARTS; ++i) {
    int j = part + i * PARTS;
    float4 p = sxyz[j];
    float dx = p.x - qx, dy = p.y - qy, dz = p.z - qz;
    float d2 = fmaf(dx, dx, fmaf(dy, dy, dz * dz));
    if (d2 < bd2) {
      bd2 = d2; bi2 = j;
      if (bd2 < bd1) { float t = bd1; bd1 = bd2; bd2 = t; int ti = bi1; bi1 = bi2; bi2 = ti; }
      if (bd1 < bd0) { float t = bd0; bd0 = bd1; bd1 = t; int ti = bi0; bi0 = bi1; bi1 = ti; }
    }
  }
  md[q][part * 3 + 0] = bd0; mi[q][part * 3 + 0] = bi0;
  md[q][part * 3 + 1] = bd1; mi[q][part * 3 + 1] = bi1;
  md[q][part * 3 + 2] = bd2; mi[q][part * 3 + 2] = bi2;
  __syncthreads();

  if (tid < QPB) {
    int qq = tid;
    float fb0 = 1e30f, fb1 = 1e30f, fb2 = 1e30f;
    int fi0 = -1, fi1 = -1, fi2 = -1;
    // cross-part merge with explicit index tiebreak (matches stable top_k)
    for (int u = 0; u < PARTS * 3; ++u) {
      float d = md[qq][u]; int ix = mi[qq][u];
      if (d < fb2 || (d == fb2 && ix < fi2)) {
        fb2 = d; fi2 = ix;
        if (fb2 < fb1 || (fb2 == fb1 && fi2 < fi1)) {
          float t = fb1; fb1 = fb2; fb2 = t; int ti = fi1; fi1 = fi2; fi2 = ti;
        }
        if (fb1 < fb0 || (fb1 == fb0 && fi1 < fi0)) {
          float t = fb0; fb0 = fb1; fb1 = t; int ti = fi0; fi0 = fi1; fi1 = ti;
        }
      }
    }
    float d0 = sqrtf(fb0), d1 = sqrtf(fb1), d2f = sqrtf(fb2);
    float inv0 = 1.0f / (d0 + 1e-8f);
    float inv1 = 1.0f / (d1 + 1e-8f);
    float inv2 = 1.0f / (d2f + 1e-8f);
    float s = inv0 + inv1 + inv2;
    wq[qq][0] = inv0 / s; wq[qq][1] = inv1 / s; wq[qq][2] = inv2 / s;
    iq[qq][0] = fi0; iq[qq][1] = fi1; iq[qq][2] = fi2;
  }
  __syncthreads();

  // interpolation + skip copy: wave-per-query, lane = 8 interp ch + 4 skip ch
  int wid = tid >> 6, lane = tid & 63;
  for (int qq = wid * 8; qq < wid * 8 + 8; ++qq) {
    int qm2 = blk * QPB + qq;
    float w0 = wq[qq][0], w1 = wq[qq][1], w2 = wq[qq][2];
    const float* f0 = feat_lo + ((size_t)b * SS + iq[qq][0]) * CLO + lane * 8;
    const float* f1 = feat_lo + ((size_t)b * SS + iq[qq][1]) * CLO + lane * 8;
    const float* f2 = feat_lo + ((size_t)b * SS + iq[qq][2]) * CLO + lane * 8;
    float4 a0 = ((const float4*)f0)[0], a1 = ((const float4*)f0)[1];
    float4 c0 = ((const float4*)f1)[0], c1 = ((const float4*)f1)[1];
    float4 e0 = ((const float4*)f2)[0], e1 = ((const float4*)f2)[1];
    float av[8];
    av[0] = w0 * a0.x + w1 * c0.x + w2 * e0.x;
    av[1] = w0 * a0.y + w1 * c0.y + w2 * e0.y;
    av[2] = w0 * a0.z + w1 * c0.z + w2 * e0.z;
    av[3] = w0 * a0.w + w1 * c0.w + w2 * e0.w;
    av[4] = w0 * a1.x + w1 * c1.x + w2 * e1.x;
    av[5] = w0 * a1.y + w1 * c1.y + w2 * e1.y;
    av[6] = w0 * a1.z + w1 * c1.z + w2 * e1.z;
    av[7] = w0 * a1.w + w1 * c1.w + w2 * e1.w;
    u16 ph[8];
#pragma unroll
    for (int c = 0; c < 8; ++c) ph[c] = f2bf(av[c]);
    uint4 st; __builtin_memcpy(&st, ph, 16);
    *(uint4*)(fused + (size_t)qm2 * CIN + CSKIP + lane * 8) = st;

    float4 sk = *(const float4*)(feat_skip + (size_t)qm2 * CSKIP + lane * 4);
    u16 p4[4];
    p4[0] = f2bf(sk.x); p4[1] = f2bf(sk.y); p4[2] = f2bf(sk.z); p4[3] = f2bf(sk.w);
    uint2 st2; __builtin_memcpy(&st2, p4, 8);
    *(uint2*)(fused + (size_t)qm2 * CIN + lane * 4) = st2;
  }
}

// ---------------------------------------------------------------------------
// K2: GEMM1  h = relu(fused @ W1 + b1), 128x128 tile, global_load_lds staging
// ---------------------------------------------------------------------------
__global__ __launch_bounds__(256) void gemm1_kernel(const u16* __restrict__ A,
                                                    const u16* __restrict__ Bt,
                                                    const float* __restrict__ b1,
                                                    u16* __restrict__ H) {
  __shared__ u16 As[128 * 32];
  __shared__ u16 Bs[128 * 32];
  int tid = threadIdx.x;
  int bm = blockIdx.x >> 1, bn = blockIdx.x & 1;
  int m0 = bm << 7, n0 = bn << 7;
  int w = tid >> 6, lane = tid & 63;
  int wr = w >> 1, wc = w & 1;
  int quad = lane >> 4, l16 = lane & 15;

  f32x4 zero = {0.f, 0.f, 0.f, 0.f};
  f32x4 acc[4][4];
#pragma unroll
  for (int tm = 0; tm < 4; ++tm)
#pragma unroll
    for (int tn = 0; tn < 4; ++tn) acc[tm][tn] = zero;

  for (int k0 = 0; k0 < CIN; k0 += 32) {
    __syncthreads();
#pragma unroll
    for (int r = 0; r < 2; ++r) {
      int u = tid + r * 256;
      int row = u >> 2, kk = (u & 3) << 3;
      gl_lds16(A + (size_t)(m0 + row) * CIN + k0 + kk, (char*)As + u * 16);
      gl_lds16(Bt + (size_t)(n0 + row) * CIN + k0 + kk, (char*)Bs + u * 16);
    }
    __syncthreads();
    short8 af[4], bf[4];
#pragma unroll
    for (int t = 0; t < 4; ++t)
      af[t] = *(const short8*)(As + ((wr * 64 + t * 16 + l16) * 32 + quad * 8));
#pragma unroll
    for (int t = 0; t < 4; ++t)
      bf[t] = *(const short8*)(Bs + ((wc * 64 + t * 16 + l16) * 32 + quad * 8));
#pragma unroll
    for (int tm = 0; tm < 4; ++tm)
#pragma unroll
      for (int tn = 0; tn < 4; ++tn)
        acc[tm][tn] = __builtin_amdgcn_mfma_f32_16x16x32_bf16(af[tm], bf[tn], acc[tm][tn], 0, 0, 0);
  }

  float bias[4];
#pragma unroll
  for (int tn = 0; tn < 4; ++tn) bias[tn] = b1[n0 + wc * 64 + tn * 16 + l16];
#pragma unroll
  for (int tm = 0; tm < 4; ++tm)
#pragma unroll
    for (int tn = 0; tn < 4; ++tn) {
      int col = n0 + wc * 64 + tn * 16 + l16;
#pragma unroll
      for (int r = 0; r < 4; ++r) {
        int row = m0 + wr * 64 + tm * 16 + quad * 4 + r;
        float v = acc[tm][tn][r] + bias[tn];
        v = v > 0.f ? v : 0.f;
        H[(size_t)row * COUT + col] = f2bf(v);
      }
    }
}

// ---------------------------------------------------------------------------
// K3: GEMM2 + bias + LayerNorm, 128x256 tile (full width), 512 threads
// ---------------------------------------------------------------------------
__global__ __launch_bounds__(512) void gemm2_ln_kernel(const u16* __restrict__ H,
                                                       const u16* __restrict__ Bt,
                                                       const float* __restrict__ b2,
                                                       const float* __restrict__ gamma,
                                                       const float* __restrict__ beta,
                                                       float* __restrict__ out) {
  __shared__ u16 As[128 * 32];
  __shared__ u16 Bs[256 * 32];
  __shared__ float red[4][128][2];
  __shared__ float stats[128][2];
  int tid = threadIdx.x;
  int m0 = blockIdx.x << 7;
  int w = tid >> 6, lane = tid & 63;
  int wr = w >> 2, wc = w & 3;
  int quad = lane >> 4, l16 = lane & 15;

  f32x4 zero = {0.f, 0.f, 0.f, 0.f};
  f32x4 acc[4][4];
#pragma unroll
  for (int tm = 0; tm < 4; ++tm)
#pragma unroll
    for (int tn = 0; tn < 4; ++tn) acc[tm][tn] = zero;

  for (int k0 = 0; k0 < COUT; k0 += 32) {
    __syncthreads();
    {
      int row = tid >> 2, kk = (tid & 3) << 3;
      gl_lds16(H + (size_t)(m0 + row) * COUT + k0 + kk, (char*)As + tid * 16);
#pragma unroll
      for (int r = 0; r < 2; ++r) {
        int ub = tid + r * 512;
        int nrow = ub >> 2, kb = (ub & 3) << 3;
        gl_lds16(Bt + (size_t)nrow * COUT + k0 + kb, (char*)Bs + ub * 16);
      }
    }
    __syncthreads();
    short8 af[4], bf[4];
#pragma unroll
    for (int t = 0; t < 4; ++t)
      af[t] = *(const short8*)(As + ((wr * 64 + t * 16 + l16) * 32 + quad * 8));
#pragma unroll
    for (int t = 0; t < 4; ++t)
      bf[t] = *(const short8*)(Bs + ((wc * 64 + t * 16 + l16) * 32 + quad * 8));
#pragma unroll
    for (int tm = 0; tm < 4; ++tm)
#pragma unroll
      for (int tn = 0; tn < 4; ++tn)
        acc[tm][tn] = __builtin_amdgcn_mfma_f32_16x16x32_bf16(af[tm], bf[tn], acc[tm][tn], 0, 0, 0);
  }

  float bias[4], g[4], be[4];
#pragma unroll
  for (int tn = 0; tn < 4; ++tn) {
    int col = wc * 64 + tn * 16 + l16;
    bias[tn] = b2[col]; g[tn] = gamma[col]; be[tn] = beta[col];
  }
#pragma unroll
  for (int tm = 0; tm < 4; ++tm)
#pragma unroll
    for (int r = 0; r < 4; ++r) {
      float s = 0.f, sq = 0.f;
#pragma unroll
      for (int tn = 0; tn < 4; ++tn) {
        float v = acc[tm][tn][r] + bias[tn];
        acc[tm][tn][r] = v;
        s += v; sq += v * v;
      }
#pragma unroll
      for (int msk = 1; msk < 16; msk <<= 1) {
        s += __shfl_xor(s, msk);
        sq += __shfl_xor(sq, msk);
      }
      if (l16 == 0) {
        int rl = wr * 64 + tm * 16 + quad * 4 + r;
        red[wc][rl][0] = s;
        red[wc][rl][1] = sq;
      }
    }
  __syncthreads();
  if (tid < 128) {
    float s = red[0][tid][0] + red[1][tid][0] + red[2][tid][0] + red[3][tid][0];
    float sq = red[0][tid][1] + red[1][tid][1] + red[2][tid][1] + red[3][tid][1];
    float mu = s * (1.f / 256.f);
    float var = sq * (1.f / 256.f) - mu * mu;
    stats[tid][0] = mu;
    stats[tid][1] = rsqrtf(var + 1e-5f);
  }
  __syncthreads();
#pragma unroll
  for (int tm = 0; tm < 4; ++tm)
#pragma unroll
    for (int r = 0; r < 4; ++r) {
      int rl = wr * 64 + tm * 16 + quad * 4 + r;
      float mu = stats[rl][0], rstd = stats[rl][1];
#pragma unroll
      for (int tn = 0; tn < 4; ++tn) {
        int col = wc * 64 + tn * 16 + l16;
        out[(size_t)(m0 + rl) * COUT + col] = (acc[tm][tn][r] - mu) * rstd * g[tn] + be[tn];
      }
    }
}

// ---------------------------------------------------------------------------
extern "C" void kernel_launch(void* const* d_in, const int* in_sizes, int n_in,
                              void* d_out, int out_size, void* d_ws, size_t ws_size,
                              hipStream_t stream) {
  const float* xyz_hi    = (const float*)d_in[0];
  const float* xyz_lo    = (const float*)d_in[1];
  const float* feat_skip = (const float*)d_in[2];
  const float* feat_lo   = (const float*)d_in[3];
  const float* W1        = (const float*)d_in[4];
  const float* b1        = (const float*)d_in[5];
  const float* W2        = (const float*)d_in[6];
  const float* b2        = (const float*)d_in[7];
  const float* gamma     = (const float*)d_in[8];
  const float* beta      = (const float*)d_in[9];
  float* out = (float*)d_out;

  char* ws = (char*)d_ws;
  u16* fused = (u16*)ws;                                   // 50331648 B
  u16* H     = (u16*)(ws + 50331648);                      // 16777216 B
  u16* W1T   = (u16*)(ws + 50331648 + 16777216);           // 393216 B
  u16* W2T   = (u16*)(ws + 50331648 + 16777216 + 393216);  // 131072 B

  wconv_kernel<<<1024, 256, 0, stream>>>(W1, W2, W1T, W2T);
  knn_interp_kernel<<<MTOT / QPB, 256, 0, stream>>>(xyz_hi, xyz_lo, feat_skip, feat_lo, fused);
  gemm1_kernel<<<(MTOT / 128) * 2, 256, 0, stream>>>(fused, W1T, b1, H);
  gemm2_ln_kernel<<<MTOT / 128, 512, 0, stream>>>(H, W2T, b2, gamma, beta, out);
}

// Round 4
// 197.396 us; speedup vs baseline: 1.2128x; 1.0570x over previous
//
#include <hip/hip_runtime.h>
#include <hip/hip_bf16.h>
#include <stdint.h>

typedef unsigned short u16;
typedef __attribute__((ext_vector_type(8))) short short8;
typedef __attribute__((ext_vector_type(4))) float f32x4;

#define BB 4
#define NN 8192
#define SS 2048
#define MTOT 32768
#define CSKIP 256
#define CLO 512
#define CIN 768
#define COUT 256

__device__ __forceinline__ u16 f2bf(float f) {
  unsigned u = __float_as_uint(f);
  u += 0x7fffu + ((u >> 16) & 1u);
  return (u16)(u >> 16);
}

__device__ __forceinline__ void gl_lds16(const void* g, void* l) {
  __builtin_amdgcn_global_load_lds(
      (const __attribute__((address_space(1))) void*)g,
      (__attribute__((address_space(3))) void*)l, 16, 0, 0);
}

// ---------------------------------------------------------------------------
// K0: weights -> bf16 transposed [n][k]
// ---------------------------------------------------------------------------
__global__ __launch_bounds__(256) void wconv_kernel(const float* __restrict__ W1,
                                                    const float* __restrict__ W2,
                                                    u16* __restrict__ W1T,
                                                    u16* __restrict__ W2T) {
  int i = blockIdx.x * 256 + threadIdx.x;
  if (i < CIN * COUT) {
    int n = i / CIN, k = i - n * CIN;
    W1T[i] = f2bf(W1[(size_t)k * COUT + n]);
  } else if (i < CIN * COUT + COUT * COUT) {
    int j = i - CIN * COUT;
    int n = j >> 8, k = j & 255;
    W2T[j] = f2bf(W2[(size_t)k * COUT + n]);
  }
}

// ---------------------------------------------------------------------------
// K1: KNN only (K=3). Broadcast layout: lane = query (64/block), wave = part
// (8 waves x 256 contiguous candidates each). DIFF-FORM fp32 distances
// (dx^2+dy^2+dz^2) — expansion form cancels catastrophically and flips
// near-tie neighbors (R3 failure, absmax 0.66). LDS reads are wave-uniform
// -> broadcast, conflict-free.
// ---------------------------------------------------------------------------
__global__ __launch_bounds__(512) void knn_kernel(
    const float* __restrict__ xyz_hi, const float* __restrict__ xyz_lo,
    float* __restrict__ wq_g, int* __restrict__ iq_g) {
  __shared__ float4 sxyz[SS];          // 32 KB: (x, y, z, 0)
  __shared__ float md[8][64][3];
  __shared__ int   mi[8][64][3];

  int tid = threadIdx.x;
  int blk = blockIdx.x;
  int b = blk >> 7;                    // 128 blocks per batch
  const float* xl = xyz_lo + (size_t)b * SS * 3;
  for (int j = tid; j < SS; j += 512)
    sxyz[j] = make_float4(xl[j * 3 + 0], xl[j * 3 + 1], xl[j * 3 + 2], 0.f);
  __syncthreads();

  int wave = tid >> 6, lane = tid & 63;
  int qm = blk * 64 + lane;
  float qx = xyz_hi[(size_t)qm * 3 + 0];
  float qy = xyz_hi[(size_t)qm * 3 + 1];
  float qz = xyz_hi[(size_t)qm * 3 + 2];

  float b0 = 1e30f, b1 = 1e30f, b2 = 1e30f;
  int i0 = -1, i1 = -1, i2 = -1;
  int j0 = wave * 256;
#pragma unroll 4
  for (int jj = 0; jj < 256; ++jj) {
    int j = j0 + jj;
    float4 p = sxyz[j];                // uniform address -> broadcast, free
    float dx = p.x - qx, dy = p.y - qy, dz = p.z - qz;
    float d = fmaf(dx, dx, fmaf(dy, dy, dz * dz));
    // branchless 3-deep insert, strict < => stable (earliest index on ties)
    bool c = d < b2;
    b2 = c ? d : b2; i2 = c ? j : i2;
    bool s = b2 < b1;
    float tb = b1; b1 = s ? b2 : b1; b2 = s ? tb : b2;
    int ti = i1;   i1 = s ? i2 : i1; i2 = s ? ti : i2;
    bool v = b1 < b0;
    float ub = b0; b0 = v ? b1 : b0; b1 = v ? ub : b1;
    int ui = i0;   i0 = v ? i1 : i0; i1 = v ? ui : i1;
  }
  md[wave][lane][0] = b0; mi[wave][lane][0] = i0;
  md[wave][lane][1] = b1; mi[wave][lane][1] = i1;
  md[wave][lane][2] = b2; mi[wave][lane][2] = i2;
  __syncthreads();

  if (tid < 64) {
    int q = tid;
    float fb0 = 1e30f, fb1 = 1e30f, fb2 = 1e30f;
    int fi0 = -1, fi1 = -1, fi2 = -1;
    for (int p = 0; p < 8; ++p)
#pragma unroll
      for (int s = 0; s < 3; ++s) {
        float d = md[p][q][s]; int ix = mi[p][q][s];
        if (d < fb2 || (d == fb2 && ix < fi2)) {
          fb2 = d; fi2 = ix;
          if (fb2 < fb1 || (fb2 == fb1 && fi2 < fi1)) {
            float t = fb1; fb1 = fb2; fb2 = t; int ti = fi1; fi1 = fi2; fi2 = ti;
          }
          if (fb1 < fb0 || (fb1 == fb0 && fi1 < fi0)) {
            float t = fb0; fb0 = fb1; fb1 = t; int ti = fi0; fi0 = fi1; fi1 = ti;
          }
        }
      }
    int qm2 = blk * 64 + q;
    float d0 = sqrtf(fb0), d1 = sqrtf(fb1), d2 = sqrtf(fb2);
    float inv0 = 1.0f / (d0 + 1e-8f);
    float inv1 = 1.0f / (d1 + 1e-8f);
    float inv2 = 1.0f / (d2 + 1e-8f);
    float s = inv0 + inv1 + inv2;
    wq_g[(size_t)qm2 * 3 + 0] = inv0 / s;
    wq_g[(size_t)qm2 * 3 + 1] = inv1 / s;
    wq_g[(size_t)qm2 * 3 + 2] = inv2 / s;
    iq_g[(size_t)qm2 * 3 + 0] = fi0;
    iq_g[(size_t)qm2 * 3 + 1] = fi1;
    iq_g[(size_t)qm2 * 3 + 2] = fi2;
  }
}

// ---------------------------------------------------------------------------
// K2: fused GEMM1: A = [feat_skip | IDW-interp(feat_lo)] built on the fly in
// LDS per 128x32 k-chunk; h = relu(A @ W1 + b1) -> H (bf16).
// 512 thr (8 waves 2x4), tile 128x256 (full N), grid = 256.
// ---------------------------------------------------------------------------
__global__ __launch_bounds__(512) void gemm1_fused_kernel(
    const float* __restrict__ feat_skip, const float* __restrict__ feat_lo,
    const float* __restrict__ wq_g, const int* __restrict__ iq_g,
    const u16* __restrict__ W1T, const float* __restrict__ b1,
    u16* __restrict__ H) {
  __shared__ u16 As[128 * 32];   // 8 KB
  __shared__ u16 Bs[256 * 32];   // 16 KB
  int tid = threadIdx.x;
  int m0 = blockIdx.x << 7;
  int b = blockIdx.x >> 6;       // 64 blocks per batch
  int w = tid >> 6, lane = tid & 63;
  int wr = w >> 2, wc = w & 3;
  int quad = lane >> 4, l16 = lane & 15;

  // staging assignment: thread -> (row, 8-channel slice)
  int srow = tid >> 2;           // 0..127
  int sc8 = (tid & 3) << 3;      // 0,8,16,24
  float w0 = wq_g[(size_t)(m0 + srow) * 3 + 0];
  float w1 = wq_g[(size_t)(m0 + srow) * 3 + 1];
  float w2 = wq_g[(size_t)(m0 + srow) * 3 + 2];
  int i0 = iq_g[(size_t)(m0 + srow) * 3 + 0];
  int i1 = iq_g[(size_t)(m0 + srow) * 3 + 1];
  int i2 = iq_g[(size_t)(m0 + srow) * 3 + 2];
  const float* fl0 = feat_lo + ((size_t)b * SS + i0) * CLO + sc8;
  const float* fl1 = feat_lo + ((size_t)b * SS + i1) * CLO + sc8;
  const float* fl2 = feat_lo + ((size_t)b * SS + i2) * CLO + sc8;
  const float* fsk = feat_skip + (size_t)(m0 + srow) * CSKIP + sc8;
  u16* As_dst = As + srow * 32 + sc8;

  f32x4 zero = {0.f, 0.f, 0.f, 0.f};
  f32x4 acc[4][4];
#pragma unroll
  for (int tm = 0; tm < 4; ++tm)
#pragma unroll
    for (int tn = 0; tn < 4; ++tn) acc[tm][tn] = zero;

  for (int kc = 0; kc < 24; ++kc) {
    __syncthreads();
    // B staging: W1T chunk 256x32 via global_load_lds x2
#pragma unroll
    for (int r = 0; r < 2; ++r) {
      int u = tid + r * 512;
      int nrow = u >> 2, kb = (u & 3) << 3;
      gl_lds16(W1T + (size_t)nrow * CIN + kc * 32 + kb, (char*)Bs + u * 16);
    }
    // A staging: compute 8 channels -> bf16 -> one ds_write_b128
    float av[8];
    if (kc < 8) {
      float4 x0 = *(const float4*)(fsk + kc * 32);
      float4 x1 = *(const float4*)(fsk + kc * 32 + 4);
      av[0] = x0.x; av[1] = x0.y; av[2] = x0.z; av[3] = x0.w;
      av[4] = x1.x; av[5] = x1.y; av[6] = x1.z; av[7] = x1.w;
    } else {
      int c = (kc - 8) * 32;
      float4 a0 = *(const float4*)(fl0 + c), a1 = *(const float4*)(fl0 + c + 4);
      float4 c0 = *(const float4*)(fl1 + c), c1 = *(const float4*)(fl1 + c + 4);
      float4 e0 = *(const float4*)(fl2 + c), e1 = *(const float4*)(fl2 + c + 4);
      av[0] = fmaf(w0, a0.x, fmaf(w1, c0.x, w2 * e0.x));
      av[1] = fmaf(w0, a0.y, fmaf(w1, c0.y, w2 * e0.y));
      av[2] = fmaf(w0, a0.z, fmaf(w1, c0.z, w2 * e0.z));
      av[3] = fmaf(w0, a0.w, fmaf(w1, c0.w, w2 * e0.w));
      av[4] = fmaf(w0, a1.x, fmaf(w1, c1.x, w2 * e1.x));
      av[5] = fmaf(w0, a1.y, fmaf(w1, c1.y, w2 * e1.y));
      av[6] = fmaf(w0, a1.z, fmaf(w1, c1.z, w2 * e1.z));
      av[7] = fmaf(w0, a1.w, fmaf(w1, c1.w, w2 * e1.w));
    }
    union { __hip_bfloat162 h2[4]; uint4 u4; } pk;
#pragma unroll
    for (int c = 0; c < 4; ++c)
      pk.h2[c] = __float22bfloat162_rn(make_float2(av[2 * c], av[2 * c + 1]));
    *(uint4*)As_dst = pk.u4;
    __syncthreads();

    short8 af[4], bf[4];
#pragma unroll
    for (int t = 0; t < 4; ++t)
      af[t] = *(const short8*)(As + ((wr * 64 + t * 16 + l16) * 32 + quad * 8));
#pragma unroll
    for (int t = 0; t < 4; ++t)
      bf[t] = *(const short8*)(Bs + ((wc * 64 + t * 16 + l16) * 32 + quad * 8));
#pragma unroll
    for (int tm = 0; tm < 4; ++tm)
#pragma unroll
      for (int tn = 0; tn < 4; ++tn)
        acc[tm][tn] = __builtin_amdgcn_mfma_f32_16x16x32_bf16(af[tm], bf[tn], acc[tm][tn], 0, 0, 0);
  }

  float bias[4];
#pragma unroll
  for (int tn = 0; tn < 4; ++tn) bias[tn] = b1[wc * 64 + tn * 16 + l16];
#pragma unroll
  for (int tm = 0; tm < 4; ++tm)
#pragma unroll
    for (int tn = 0; tn < 4; ++tn) {
      int col = wc * 64 + tn * 16 + l16;
#pragma unroll
      for (int r = 0; r < 4; ++r) {
        int row = m0 + wr * 64 + tm * 16 + quad * 4 + r;
        float v = acc[tm][tn][r] + bias[tn];
        v = v > 0.f ? v : 0.f;
        H[(size_t)row * COUT + col] = f2bf(v);
      }
    }
}

// ---------------------------------------------------------------------------
// K3: GEMM2 + bias + LayerNorm, 128x256 tile (full width), 512 threads
// ---------------------------------------------------------------------------
__global__ __launch_bounds__(512) void gemm2_ln_kernel(const u16* __restrict__ H,
                                                       const u16* __restrict__ Bt,
                                                       const float* __restrict__ b2,
                                                       const float* __restrict__ gamma,
                                                       const float* __restrict__ beta,
                                                       float* __restrict__ out) {
  __shared__ u16 As[128 * 32];
  __shared__ u16 Bs[256 * 32];
  __shared__ float red[4][128][2];
  __shared__ float stats[128][2];
  int tid = threadIdx.x;
  int m0 = blockIdx.x << 7;
  int w = tid >> 6, lane = tid & 63;
  int wr = w >> 2, wc = w & 3;
  int quad = lane >> 4, l16 = lane & 15;

  f32x4 zero = {0.f, 0.f, 0.f, 0.f};
  f32x4 acc[4][4];
#pragma unroll
  for (int tm = 0; tm < 4; ++tm)
#pragma unroll
    for (int tn = 0; tn < 4; ++tn) acc[tm][tn] = zero;

  for (int k0 = 0; k0 < COUT; k0 += 32) {
    __syncthreads();
    {
      int row = tid >> 2, kk = (tid & 3) << 3;
      gl_lds16(H + (size_t)(m0 + row) * COUT + k0 + kk, (char*)As + tid * 16);
#pragma unroll
      for (int r = 0; r < 2; ++r) {
        int ub = tid + r * 512;
        int nrow = ub >> 2, kb = (ub & 3) << 3;
        gl_lds16(Bt + (size_t)nrow * COUT + k0 + kb, (char*)Bs + ub * 16);
      }
    }
    __syncthreads();
    short8 af[4], bf[4];
#pragma unroll
    for (int t = 0; t < 4; ++t)
      af[t] = *(const short8*)(As + ((wr * 64 + t * 16 + l16) * 32 + quad * 8));
#pragma unroll
    for (int t = 0; t < 4; ++t)
      bf[t] = *(const short8*)(Bs + ((wc * 64 + t * 16 + l16) * 32 + quad * 8));
#pragma unroll
    for (int tm = 0; tm < 4; ++tm)
#pragma unroll
      for (int tn = 0; tn < 4; ++tn)
        acc[tm][tn] = __builtin_amdgcn_mfma_f32_16x16x32_bf16(af[tm], bf[tn], acc[tm][tn], 0, 0, 0);
  }

  float bias[4], g[4], be[4];
#pragma unroll
  for (int tn = 0; tn < 4; ++tn) {
    int col = wc * 64 + tn * 16 + l16;
    bias[tn] = b2[col]; g[tn] = gamma[col]; be[tn] = beta[col];
  }
#pragma unroll
  for (int tm = 0; tm < 4; ++tm)
#pragma unroll
    for (int r = 0; r < 4; ++r) {
      float s = 0.f, sq = 0.f;
#pragma unroll
      for (int tn = 0; tn < 4; ++tn) {
        float v = acc[tm][tn][r] + bias[tn];
        acc[tm][tn][r] = v;
        s += v; sq += v * v;
      }
#pragma unroll
      for (int msk = 1; msk < 16; msk <<= 1) {
        s += __shfl_xor(s, msk);
        sq += __shfl_xor(sq, msk);
      }
      if (l16 == 0) {
        int rl = wr * 64 + tm * 16 + quad * 4 + r;
        red[wc][rl][0] = s;
        red[wc][rl][1] = sq;
      }
    }
  __syncthreads();
  if (tid < 128) {
    float s = red[0][tid][0] + red[1][tid][0] + red[2][tid][0] + red[3][tid][0];
    float sq = red[0][tid][1] + red[1][tid][1] + red[2][tid][1] + red[3][tid][1];
    float mu = s * (1.f / 256.f);
    float var = sq * (1.f / 256.f) - mu * mu;
    stats[tid][0] = mu;
    stats[tid][1] = rsqrtf(var + 1e-5f);
  }
  __syncthreads();
#pragma unroll
  for (int tm = 0; tm < 4; ++tm)
#pragma unroll
    for (int r = 0; r < 4; ++r) {
      int rl = wr * 64 + tm * 16 + quad * 4 + r;
      float mu = stats[rl][0], rstd = stats[rl][1];
#pragma unroll
      for (int tn = 0; tn < 4; ++tn) {
        int col = wc * 64 + tn * 16 + l16;
        out[(size_t)(m0 + rl) * COUT + col] = (acc[tm][tn][r] - mu) * rstd * g[tn] + be[tn];
      }
    }
}

// ---------------------------------------------------------------------------
extern "C" void kernel_launch(void* const* d_in, const int* in_sizes, int n_in,
                              void* d_out, int out_size, void* d_ws, size_t ws_size,
                              hipStream_t stream) {
  const float* xyz_hi    = (const float*)d_in[0];
  const float* xyz_lo    = (const float*)d_in[1];
  const float* feat_skip = (const float*)d_in[2];
  const float* feat_lo   = (const float*)d_in[3];
  const float* W1        = (const float*)d_in[4];
  const float* b1        = (const float*)d_in[5];
  const float* W2        = (const float*)d_in[6];
  const float* b2        = (const float*)d_in[7];
  const float* gamma     = (const float*)d_in[8];
  const float* beta      = (const float*)d_in[9];
  float* out = (float*)d_out;

  char* ws = (char*)d_ws;
  u16*   H    = (u16*)ws;                     // 16777216
  u16*   W1T  = (u16*)(ws + 16777216);        // 393216
  u16*   W2T  = (u16*)(ws + 16777216 + 393216);            // 131072
  float* wq_g = (float*)(ws + 16777216 + 393216 + 131072); // 393216
  int*   iq_g = (int*)(ws + 16777216 + 393216 + 131072 + 393216); // 393216

  wconv_kernel<<<1024, 256, 0, stream>>>(W1, W2, W1T, W2T);
  knn_kernel<<<MTOT / 64, 512, 0, stream>>>(xyz_hi, xyz_lo, wq_g, iq_g);
  gemm1_fused_kernel<<<MTOT / 128, 512, 0, stream>>>(feat_skip, feat_lo, wq_g, iq_g, W1T, b1, H);
  gemm2_ln_kernel<<<MTOT / 128, 512, 0, stream>>>(H, W2T, b2, gamma, beta, out);
}